// Round 1
// baseline (35026.917 us; speedup 1.0000x reference)
//
#include <hip/hip_runtime.h>
#include <hip/hip_bf16.h>
#include <cstdint>

// ============================================================================
// 2-layer LSTM prefix + 59-step decode, fused persistent-kernel design.
//
// Sequential chain as 376 "super-steps" inside ONE persistent kernel
// (256 blocks x 256 thr) separated by a custom device-scope grid barrier.
//   SS 0..256   : prefix, layer0@t=s (WG 0..127) || layer1@t=s-1 (WG 128..255)
//   SS 257+2i   : decode cell0 (gates via Weff-fused W) + y output columns
//   SS 258+2i   : decode cell1
//   SS 375      : final y (step 59)
// All GEMMs: fp16 MFMA 16x16x32, fp32 accum; c-state fp32; h-state fp16
// double-buffered (version counters pick read/write parity).
// Weights repacked fp16, rows permuted row'=4*unit+gate so each 32-col tile
// holds complete i,f,g,o quads -> cell update is quad-local (shfl_xor).
// Workspace required ~61.1 MB.
// ============================================================================

#define LROW 136  // LDS B-tile row length in halves: 128 + 8 pad

typedef _Float16 half_t;
typedef _Float16 half8 __attribute__((ext_vector_type(8)));
typedef _Float16 half4v __attribute__((ext_vector_type(4)));
typedef float float4v __attribute__((ext_vector_type(4)));

__device__ __forceinline__ float sigm_(float x) { return 1.0f / (1.0f + __expf(-x)); }
__device__ __forceinline__ float tanh_(float x) {
  float ax = fabsf(x);
  float e = __expf(-2.0f * ax);
  float t = (1.0f - e) / (1.0f + e);
  return x < 0.0f ? -t : t;
}

// Device-scope grid barrier: monotonic counter, no reset (no ABA).
// __threadfence() = agent-scope fence -> L2 writeback/invalidate for
// cross-XCD visibility of h/c state (G16).
__device__ __forceinline__ void grid_barrier(int* cnt, int target) {
  __syncthreads();
  if (threadIdx.x == 0) {
    __threadfence();
    __hip_atomic_fetch_add(cnt, 1, __ATOMIC_RELEASE, __HIP_MEMORY_SCOPE_AGENT);
    while (__hip_atomic_load(cnt, __ATOMIC_ACQUIRE, __HIP_MEMORY_SCOPE_AGENT) < target) {
      __builtin_amdgcn_s_sleep(1);
    }
  }
  __syncthreads();
  __threadfence();
}

// One [128 x 32] output tile: C = A(128xKtot) * W(32 rows x Ktot)^T.
// A = concat of two fp16 sources (K0 then rest). W rows staged to LDS
// (double-buffered, 128-k chunks); A fragments loaded direct from global.
// Wave wv owns rows [32*wv, 32*wv+32).
__device__ __forceinline__ void gemm_item(
    const half_t* __restrict__ A0, int a0s, int K0,
    const half_t* __restrict__ A1, int a1s,
    const half_t* __restrict__ Wb, int wstr, int Ktot,
    half_t* ldsB, int tid, float4v acc[2][2]) {
  const int wv = tid >> 6, l = tid & 63;
  const int lrow = l & 15, lq = l >> 4;
  const int srow = tid >> 3, soff = (tid & 7) * 16;

  uint4 st0, st1;
  {
    const half_t* wp = Wb + (long)srow * wstr + soff;
    st0 = *(const uint4*)(wp);
    st1 = *(const uint4*)(wp + 8);
    half_t* lp = ldsB + srow * LROW + soff;
    *(uint4*)lp = st0;
    *(uint4*)(lp + 8) = st1;
  }
  __syncthreads();
  const int nch = Ktot >> 7;
  for (int c = 0; c < nch; ++c) {
    if (c + 1 < nch) {
      const half_t* wp = Wb + (long)srow * wstr + (c + 1) * 128 + soff;
      st0 = *(const uint4*)(wp);
      st1 = *(const uint4*)(wp + 8);
    }
    const int kb = c << 7;
    const half_t* As;
    int ast, kl;
    if (kb < K0) { As = A0; ast = a0s; kl = kb; }
    else { As = A1; ast = a1s; kl = kb - K0; }
    const half_t* a0p = As + (wv * 32 + lrow) * ast + kl + lq * 8;
    const half_t* a1p = a0p + 16 * ast;
    const half_t* bp = ldsB + (c & 1) * (32 * LROW) + lq * 8;
#pragma unroll
    for (int ks = 0; ks < 4; ++ks) {
      half8 af0 = *(const half8*)(a0p + ks * 32);
      half8 af1 = *(const half8*)(a1p + ks * 32);
      half8 bf0 = *(const half8*)(bp + lrow * LROW + ks * 32);
      half8 bf1 = *(const half8*)(bp + (lrow + 16) * LROW + ks * 32);
      acc[0][0] = __builtin_amdgcn_mfma_f32_16x16x32_f16(af0, bf0, acc[0][0], 0, 0, 0);
      acc[0][1] = __builtin_amdgcn_mfma_f32_16x16x32_f16(af0, bf1, acc[0][1], 0, 0, 0);
      acc[1][0] = __builtin_amdgcn_mfma_f32_16x16x32_f16(af1, bf0, acc[1][0], 0, 0, 0);
      acc[1][1] = __builtin_amdgcn_mfma_f32_16x16x32_f16(af1, bf1, acc[1][1], 0, 0, 0);
    }
    __syncthreads();
    if (c + 1 < nch) {
      half_t* lp = ldsB + ((c + 1) & 1) * (32 * LROW) + srow * LROW + soff;
      *(uint4*)lp = st0;
      *(uint4*)(lp + 8) = st1;
      __syncthreads();
    }
  }
}

// LSTM cell epilogue for a [128x32] gate tile (cols = 8 units x 4 gates).
// D layout: col = lane&15, row = (lane>>4)*4 + reg. Gates for one unit live
// in the 4 lanes of a quad -> gather via shfl_xor; lane q writes reg q.
__device__ __forceinline__ void epilogue_gates(
    float4v acc[2][2], int col0, const float* __restrict__ biasArr,
    float* __restrict__ cArr, half_t* __restrict__ hDst, int tid) {
  const int wv = tid >> 6, l = tid & 63;
  const int lrow = l & 15, lq = l >> 4, q = l & 3;
#pragma unroll
  for (int m = 0; m < 2; ++m)
#pragma unroll
    for (int n = 0; n < 2; ++n) {
      const int col = col0 + n * 16 + lrow;
      const float bias = biasArr[col];
      const int j = col >> 2;
      const int rb = wv * 32 + m * 16 + lq * 4;
      float cn_q = 0.f, hn_q = 0.f;
#pragma unroll
      for (int r = 0; r < 4; ++r) {
        float x = acc[m][n][r] + bias;
        float t1 = __shfl_xor(x, 1);
        float t2 = __shfl_xor(x, 2);
        float t3 = __shfl_xor(x, 3);
        // gate k value sits at quad-lane k: my copy of it = {x,t1,t2,t3}[k^q]
        float gi = (q == 0) ? x : (q == 1 ? t1 : (q == 2 ? t2 : t3));
        float gf = (q == 1) ? x : (q == 0 ? t1 : (q == 3 ? t2 : t3));
        float gg = (q == 2) ? x : (q == 3 ? t1 : (q == 0 ? t2 : t3));
        float go = (q == 3) ? x : (q == 2 ? t1 : (q == 1 ? t2 : t3));
        float iv = sigm_(gi), fv = sigm_(gf), gv = tanh_(gg), ov = sigm_(go);
        float cold = cArr[(rb + r) * 1024 + j];
        float cnew = fv * cold + iv * gv;
        float hnew = ov * tanh_(cnew);
        if (r == q) { cn_q = cnew; hn_q = hnew; }
      }
      cArr[(rb + q) * 1024 + j] = cn_q;
      hDst[(rb + q) * 1024 + j] = (half_t)hn_q;
    }
}

__device__ __forceinline__ void epilogue_y(
    float4v acc[2][2], int ycol0, const float* __restrict__ biasArr,
    float* __restrict__ outp, int tid) {
  const int wv = tid >> 6, l = tid & 63;
  const int lrow = l & 15, lq = l >> 4;
#pragma unroll
  for (int m = 0; m < 2; ++m)
#pragma unroll
    for (int n = 0; n < 2; ++n) {
      const int d = ycol0 + n * 16 + lrow;
      const float bias = biasArr[d];
      const int rb = wv * 32 + m * 16 + lq * 4;
#pragma unroll
      for (int r = 0; r < 4; ++r) {
        outp[(rb + r) * 15360 + d] = acc[m][n][r] + bias;
      }
    }
}

#define ZACC float4v acc[2][2]; { float4v z = {0.f, 0.f, 0.f, 0.f}; \
  acc[0][0] = z; acc[0][1] = z; acc[1][0] = z; acc[1][1] = z; }

__global__ void __launch_bounds__(256, 1) k_lstm(
    const half_t* __restrict__ W0, const half_t* __restrict__ W1,
    const half_t* __restrict__ WD0, const half_t* __restrict__ XH,
    half_t* __restrict__ H0H, half_t* __restrict__ H1H,
    float* __restrict__ C0, float* __restrict__ C1,
    const float* __restrict__ B0P, const float* __restrict__ B1P,
    const float* __restrict__ BD0P, float* __restrict__ out, int* cnt) {
  __shared__ half_t ldsB[2 * 32 * LROW];
  const int w = blockIdx.x, tid = threadIdx.x;
  const int HS = 128 * 1024;  // one h buffer, in halves
  int v0 = 0, v1 = 0;
  for (int s = 0; s < 376; ++s) {
    const int rb0 = v0 & 1, rb1 = v1 & 1;
    bool up0 = false, up1 = false;
    if (s <= 256) {  // ---- prefix: L0@t=s || L1@t=s-1 ----
      up0 = (s <= 255);
      up1 = (s >= 1);
      if (w < 128) {
        if (s <= 255) {
          ZACC;
          gemm_item(XH + s * 256, 65536, 256,
                    H0H + rb0 * HS, 1024,
                    W0 + (long)(w * 32) * 1280, 1280, 1280, ldsB, tid, acc);
          epilogue_gates(acc, w * 32, B0P, C0, H0H + (1 - rb0) * HS, tid);
        }
      } else {
        if (s >= 1) {
          ZACC;
          const int cw = (w - 128) * 32;
          gemm_item(H0H + rb0 * HS, 1024, 1024,
                    H1H + rb1 * HS, 1024,
                    W1 + (long)cw * 2048, 2048, 2048, ldsB, tid, acc);
          epilogue_gates(acc, cw, B1P, C1, H1H + (1 - rb1) * HS, tid);
        }
      }
    } else if (s < 375) {  // ---- decode ----
      const int d = s - 257;
      if ((d & 1) == 0) {  // cell0 (Weff-fused) + y output
        up0 = true;
        const int i = d >> 1;
        if (w < 128) {
          ZACC;
          gemm_item(H1H + rb1 * HS, 1024, 1024,
                    H0H + rb0 * HS, 1024,
                    WD0 + (long)(w * 32) * 2048, 2048, 2048, ldsB, tid, acc);
          epilogue_gates(acc, w * 32, BD0P, C0, H0H + (1 - rb0) * HS, tid);
        } else if (w < 136) {
          ZACC;
          const int yc = (w - 128) * 32;
          gemm_item(H1H + rb1 * HS, 1024, 1024, (const half_t*)0, 0,
                    WD0 + (long)(4096 + yc) * 2048, 2048, 1024, ldsB, tid, acc);
          epilogue_y(acc, yc, BD0P + 4096, out + i * 256, tid);
        }
      } else {  // cell1
        up1 = true;
        if (w < 128) {
          ZACC;
          const int cw = w * 32;
          gemm_item(H0H + rb0 * HS, 1024, 1024,
                    H1H + rb1 * HS, 1024,
                    W1 + (long)cw * 2048, 2048, 2048, ldsB, tid, acc);
          epilogue_gates(acc, cw, B1P, C1, H1H + (1 - rb1) * HS, tid);
        }
      }
    } else {  // ---- s == 375: final y (step 59) ----
      if (w < 8) {
        ZACC;
        const int yc = w * 32;
        gemm_item(H1H + rb1 * HS, 1024, 1024, (const half_t*)0, 0,
                  WD0 + (long)(4096 + yc) * 2048, 2048, 1024, ldsB, tid, acc);
        epilogue_y(acc, yc, BD0P + 4096, out + 59 * 256, tid);
      }
    }
    grid_barrier(cnt, (s + 1) * 256);
    if (up0) v0++;
    if (up1) v1++;
  }
}

// ======================= setup kernels =======================

__global__ void k_cvt_x(const float* __restrict__ x, half_t* __restrict__ xh) {
  int i = blockIdx.x * blockDim.x + threadIdx.x;  // per float4
  float4 v = ((const float4*)x)[i];
  half4v h = {(half_t)v.x, (half_t)v.y, (half_t)v.z, (half_t)v.w};
  *((half4v*)xh + i) = h;
}

// Pack [Wa | Wb] rows into dst with gate-interleaved row permutation
// row' = 4*unit + gate  <->  r = gate*1024 + unit.
__global__ void k_pack_cat(const float* __restrict__ Wa, int Ka,
                           const float* __restrict__ Wb, int Kb,
                           half_t* __restrict__ dst, int dstride, int kq4) {
  int idx = blockIdx.x * blockDim.x + threadIdx.x;
  int rp = idx / kq4;
  int kq = (idx - rp * kq4) * 4;
  int r = ((rp & 3) << 10) + (rp >> 2);
  const float* src = (kq < Ka) ? (Wa + r * Ka + kq) : (Wb + r * Kb + (kq - Ka));
  float4 v = *(const float4*)src;
  half4v h = {(half_t)v.x, (half_t)v.y, (half_t)v.z, (half_t)v.w};
  *(half4v*)(dst + (long)rp * dstride + kq) = h;
}

__global__ void k_pack_wlin(const float* __restrict__ Wlin, half_t* __restrict__ dst) {
  int idx = blockIdx.x * blockDim.x + threadIdx.x;  // 65536
  int c = idx >> 8;
  int kq = (idx & 255) * 4;
  float4 v = *(const float4*)(Wlin + c * 1024 + kq);
  half4v h = {(half_t)v.x, (half_t)v.y, (half_t)v.z, (half_t)v.w};
  *(half4v*)(dst + (long)c * 2048 + kq) = h;
}

__global__ void k_bias_simple(const float* bi0, const float* bh0,
                              const float* bi1, const float* bh1,
                              const float* blin, float* b0p, float* b1p,
                              float* bD0p) {
  int rp = blockIdx.x * blockDim.x + threadIdx.x;
  if (rp < 4096) {
    int r = ((rp & 3) << 10) + (rp >> 2);
    b0p[rp] = bi0[r] + bh0[r];
    b1p[rp] = bi1[r] + bh1[r];
  } else if (rp < 4352) {
    bD0p[rp] = blin[rp - 4096];
  }
}

// biasD0p[row'] = b_ih0[r] + b_hh0[r] + dot(W_ih0[r,:], b_lin)
__global__ void k_bias_dot(const float* __restrict__ Wih0,
                           const float* __restrict__ blin,
                           const float* __restrict__ bi0,
                           const float* __restrict__ bh0,
                           float* __restrict__ bD0p) {
  int wv = threadIdx.x >> 6, l = threadIdx.x & 63;
  int r = blockIdx.x * 4 + wv;
  float s = 0.f;
#pragma unroll
  for (int c = 0; c < 4; ++c) s += Wih0[r * 256 + c * 64 + l] * blin[c * 64 + l];
#pragma unroll
  for (int o = 32; o >= 1; o >>= 1) s += __shfl_xor(s, o);
  if (l == 0) {
    int rp = ((r & 1023) << 2) | (r >> 10);
    bD0p[rp] = bi0[r] + bh0[r] + s;
  }
}

// Weff = W_ih0(4096x256) @ W_lin(256x1024), fp32, written fp16 (permuted rows)
// into WcatD0[:, 0:1024].
__global__ void k_weff(const float* __restrict__ Wih0,
                       const float* __restrict__ Wlin,
                       half_t* __restrict__ WD0) {
  __shared__ float At[64][65];
  __shared__ float Bt[64][65];
  const int rt = blockIdx.x, jt = blockIdx.y;
  const int tid = threadIdx.x;
  const int tx = tid & 15, ty = tid >> 4;
  float acc[4][4] = {};
  for (int k0 = 0; k0 < 256; k0 += 64) {
    __syncthreads();
#pragma unroll
    for (int i = 0; i < 16; ++i) {
      int lin = tid + 256 * i;
      int rr = lin >> 6, kk = lin & 63;
      At[rr][kk] = Wih0[(rt * 64 + rr) * 256 + k0 + kk];
      Bt[rr][kk] = Wlin[(k0 + rr) * 1024 + jt * 64 + kk];
    }
    __syncthreads();
    for (int kk = 0; kk < 64; ++kk) {
      float a[4], b[4];
#pragma unroll
      for (int i = 0; i < 4; ++i) a[i] = At[ty * 4 + i][kk];
#pragma unroll
      for (int i = 0; i < 4; ++i) b[i] = Bt[kk][tx * 4 + i];
#pragma unroll
      for (int i = 0; i < 4; ++i)
#pragma unroll
        for (int jx = 0; jx < 4; ++jx) acc[i][jx] += a[i] * b[jx];
    }
  }
#pragma unroll
  for (int i = 0; i < 4; ++i) {
    int r = rt * 64 + ty * 4 + i;
    int rp = ((r & 1023) << 2) | (r >> 10);
#pragma unroll
    for (int jx = 0; jx < 4; ++jx) {
      int j = jt * 64 + tx * 4 + jx;
      WD0[(long)rp * 2048 + j] = (half_t)acc[i][jx];
    }
  }
}

// ======================= launch =======================

extern "C" void kernel_launch(void* const* d_in, const int* in_sizes, int n_in,
                              void* d_out, int out_size, void* d_ws, size_t ws_size,
                              hipStream_t stream) {
  (void)in_sizes; (void)n_in; (void)out_size; (void)ws_size;
  const float* x    = (const float*)d_in[0];
  const float* Wih0 = (const float*)d_in[1];
  const float* Whh0 = (const float*)d_in[2];
  const float* bi0  = (const float*)d_in[3];
  const float* bh0  = (const float*)d_in[4];
  const float* Wih1 = (const float*)d_in[5];
  const float* Whh1 = (const float*)d_in[6];
  const float* bi1  = (const float*)d_in[7];
  const float* bh1  = (const float*)d_in[8];
  const float* Wlin = (const float*)d_in[9];
  const float* blin = (const float*)d_in[10];
  float* out = (float*)d_out;
  char* ws = (char*)d_ws;

  half_t* W0   = (half_t*)(ws + 0);         // [4096 x 1280] = [Wih0|Whh0]
  half_t* W1   = (half_t*)(ws + 10485760);  // [4096 x 2048] = [Wih1|Whh1]
  half_t* WD0  = (half_t*)(ws + 27262976);  // [4352 x 2048] = [Weff|Whh0 ; Wlin|-]
  half_t* XH   = (half_t*)(ws + 45088768);  // x as fp16
  half_t* H0H  = (half_t*)(ws + 61865984);  // 2 x [128x1024]
  half_t* H1H  = (half_t*)(ws + 62390272);
  float*  C0   = (float*)(ws + 62914560);
  float*  C1   = (float*)(ws + 63438848);
  int*    CNT  = (int*)(ws + 63963136);
  float*  B0P  = (float*)(ws + 63963392);
  float*  B1P  = (float*)(ws + 63979776);
  float*  BD0P = (float*)(ws + 63996160);
  // total ws needed: 64,013,568 bytes (~61.1 MB)

  // zero h/c state + barrier counter
  hipMemsetAsync(ws + 61865984, 0, 2097408, stream);
  k_cvt_x<<<8192, 256, 0, stream>>>(x, XH);
  k_bias_simple<<<17, 256, 0, stream>>>(bi0, bh0, bi1, bh1, blin, B0P, B1P, BD0P);
  k_bias_dot<<<1024, 256, 0, stream>>>(Wih0, blin, bi0, bh0, BD0P);
  k_pack_cat<<<5120, 256, 0, stream>>>(Wih0, 256, Whh0, 1024, W0, 1280, 320);
  k_pack_cat<<<8192, 256, 0, stream>>>(Wih1, 1024, Whh1, 1024, W1, 2048, 512);
  k_pack_cat<<<4096, 256, 0, stream>>>(Whh0, 0, Whh0, 1024, WD0 + 1024, 2048, 256);
  k_pack_wlin<<<256, 256, 0, stream>>>(Wlin, WD0 + (long)4096 * 2048);
  k_weff<<<dim3(64, 16), 256, 0, stream>>>(Wih0, Wlin, WD0);
  k_lstm<<<256, 256, 0, stream>>>(W0, W1, WD0, XH, H0H, H1H, C0, C1,
                                  B0P, B1P, BD0P, out, CNT);
}

// Round 2
// 33177.237 us; speedup vs baseline: 1.0558x; 1.0558x over previous
//
#include <hip/hip_runtime.h>
#include <hip/hip_bf16.h>
#include <cstdint>

// ============================================================================
// 2-layer LSTM prefix + 59-step decode, persistent kernel, round 2.
// Key change vs round 1: ALL layouts are MFMA-fragment-linear.
//   h/x state:  [kblock][128 rows][8 halves]   (block = 2 KB, coalesced frags)
//   weights:    per-WG packed stream [chunk][16 kblocks][32 cols][8 halves]
//   c state:    per-WG block [128 rows][8 units] fp32 (4 KB, L1-resident)
//   h epilogue: LDS 2KB tile -> one coalesced 16B/lane store per WG
// ============================================================================

typedef _Float16 half_t;
typedef _Float16 half8 __attribute__((ext_vector_type(8)));
typedef float float4v __attribute__((ext_vector_type(4)));

__device__ __forceinline__ float sigm_(float x) { return 1.0f / (1.0f + __expf(-x)); }
__device__ __forceinline__ float tanh_(float x) {
  float ax = fabsf(x);
  float e = __expf(-2.0f * ax);
  float t = (1.0f - e) / (1.0f + e);
  return x < 0.0f ? -t : t;
}

// Device-scope grid barrier: monotonic counter, agent-scope fences for
// cross-XCD h/c visibility (G16).
__device__ __forceinline__ void grid_barrier(int* cnt, int target) {
  __syncthreads();
  if (threadIdx.x == 0) {
    __threadfence();
    __hip_atomic_fetch_add(cnt, 1, __ATOMIC_RELEASE, __HIP_MEMORY_SCOPE_AGENT);
    while (__hip_atomic_load(cnt, __ATOMIC_ACQUIRE, __HIP_MEMORY_SCOPE_AGENT) < target) {
      __builtin_amdgcn_s_sleep(1);
    }
  }
  __syncthreads();
  __threadfence();
}

#define MFMA16(a, b, c) __builtin_amdgcn_mfma_f32_16x16x32_f16(a, b, c, 0, 0, 0)

// C = A(128 x K) * W(32 x K)^T for one WG.  A = concat(A0, A1) in k-blocks
// (K0b blocks from A0).  A in fragment-linear [block][128][8]; W from the
// per-WG packed stream (chunk = 128 k = 4096 halves), double-buffered in LDS.
__device__ __forceinline__ void gemm_item(
    const half_t* __restrict__ A0, const half_t* __restrict__ A1, int K0b,
    const half_t* __restrict__ Wst, int nch,
    half_t* ldsB, int tid, float4v acc[2][2]) {
  const int wv = tid >> 6, l = tid & 63;
  const int lrow = l & 15, lq = l >> 4;

  uint4 p0 = *(const uint4*)(Wst + tid * 8);
  uint4 p1 = *(const uint4*)(Wst + 2048 + tid * 8);
  *(uint4*)(ldsB + tid * 8) = p0;
  *(uint4*)(ldsB + 2048 + tid * 8) = p1;
  __syncthreads();

  for (int c = 0; c < nch; ++c) {
    if (c + 1 < nch) {
      p0 = *(const uint4*)(Wst + (c + 1) * 4096 + tid * 8);
      p1 = *(const uint4*)(Wst + (c + 1) * 4096 + 2048 + tid * 8);
    }
    const half_t* Ab = (c * 16 < K0b) ? (A0 + (long)c * 16384)
                                      : (A1 + (long)(c * 16 - K0b) * 1024);
    const half_t* ap = Ab + (wv * 32 + lrow) * 8;
    const half_t* bp = ldsB + (c & 1) * 4096 + lrow * 8;
#pragma unroll
    for (int ks = 0; ks < 4; ++ks) {
      const int blk = ks * 4 + lq;
      half8 af0 = *(const half8*)(ap + blk * 1024);
      half8 af1 = *(const half8*)(ap + blk * 1024 + 128);
      half8 bf0 = *(const half8*)(bp + blk * 256);
      half8 bf1 = *(const half8*)(bp + blk * 256 + 128);
      acc[0][0] = MFMA16(af0, bf0, acc[0][0]);
      acc[0][1] = MFMA16(af0, bf1, acc[0][1]);
      acc[1][0] = MFMA16(af1, bf0, acc[1][0]);
      acc[1][1] = MFMA16(af1, bf1, acc[1][1]);
    }
    __syncthreads();
    if (c + 1 < nch) {
      *(uint4*)(ldsB + ((c + 1) & 1) * 4096 + tid * 8) = p0;
      *(uint4*)(ldsB + ((c + 1) & 1) * 4096 + 2048 + tid * 8) = p1;
      __syncthreads();
    }
  }
}

// Cell epilogue for a [128 x 32] gate tile (cols = 8 units x 4 gates).
// D layout: col = lane&15, row = (lane>>4)*4 + reg.  Gates of one unit live
// in a quad; lane q keeps reg r==q (its own row).  c in [row][8] fp32 block;
// h staged in LDS [row][8] then copied coalesced to the global h block.
__device__ __forceinline__ void epilogue_gates(
    float4v acc[2][2], int col0, const float* __restrict__ biasArr,
    float* __restrict__ Cblk, half_t* hTile, half_t* __restrict__ hDstBlk,
    int tid) {
  const int wv = tid >> 6, l = tid & 63;
  const int lrow = l & 15, lq = l >> 4, q = l & 3;
  const int a = lrow >> 2;
#pragma unroll
  for (int m = 0; m < 2; ++m)
#pragma unroll
    for (int n = 0; n < 2; ++n) {
      const float bias = biasArr[col0 + n * 16 + lrow];
      float gi = 0.f, gf = 0.f, gg = 0.f, go = 0.f;
#pragma unroll
      for (int r = 0; r < 4; ++r) {
        float x = acc[m][n][r] + bias;
        float t1 = __shfl_xor(x, 1);
        float t2 = __shfl_xor(x, 2);
        float t3 = __shfl_xor(x, 3);
        if (r == q) {
          gi = (q == 0) ? x : (q == 1 ? t1 : (q == 2 ? t2 : t3));
          gf = (q == 1) ? x : (q == 0 ? t1 : (q == 3 ? t2 : t3));
          gg = (q == 2) ? x : (q == 3 ? t1 : (q == 0 ? t2 : t3));
          go = (q == 3) ? x : (q == 2 ? t1 : (q == 1 ? t2 : t3));
        }
      }
      const int row = wv * 32 + m * 16 + lq * 4 + q;
      const int jj = n * 4 + a;
      float iv = sigm_(gi), fv = sigm_(gf), gv = tanh_(gg), ov = sigm_(go);
      float cold = Cblk[row * 8 + jj];
      float cnew = fv * cold + iv * gv;
      float hnew = ov * tanh_(cnew);
      Cblk[row * 8 + jj] = cnew;
      hTile[row * 8 + jj] = (half_t)hnew;
    }
  __syncthreads();
  if (tid < 128) {
    *(uint4*)(hDstBlk + tid * 8) = *(const uint4*)(hTile + tid * 8);
  }
}

__device__ __forceinline__ void epilogue_y(
    float4v acc[2][2], int ycol0, const float* __restrict__ biasArr,
    float* __restrict__ outp, int tid) {
  const int wv = tid >> 6, l = tid & 63;
  const int lrow = l & 15, lq = l >> 4;
#pragma unroll
  for (int m = 0; m < 2; ++m)
#pragma unroll
    for (int n = 0; n < 2; ++n) {
      const int d = ycol0 + n * 16 + lrow;
      const float bias = biasArr[d];
      const int rb = wv * 32 + m * 16 + lq * 4;
#pragma unroll
      for (int r = 0; r < 4; ++r) {
        outp[(rb + r) * 15360 + d] = acc[m][n][r] + bias;
      }
    }
}

#define ZACC float4v acc[2][2]; { float4v z = {0.f, 0.f, 0.f, 0.f}; \
  acc[0][0] = z; acc[0][1] = z; acc[1][0] = z; acc[1][1] = z; }

__global__ void __launch_bounds__(256, 1) k_lstm(
    const half_t* __restrict__ S0, const half_t* __restrict__ S1,
    const half_t* __restrict__ SD, const half_t* __restrict__ SY,
    const half_t* __restrict__ XH,
    half_t* __restrict__ H0H, half_t* __restrict__ H1H,
    float* __restrict__ C0, float* __restrict__ C1,
    const float* __restrict__ B0P, const float* __restrict__ B1P,
    const float* __restrict__ BD0P, float* __restrict__ out, int* cnt) {
  __shared__ half_t ldsB[8192];   // W chunk double buffer (2 x 4 KB)
  __shared__ half_t hTile[1024];  // h epilogue staging (2 KB)
  const int w = blockIdx.x, tid = threadIdx.x;
  const int HS = 131072;  // one h buffer in halves (128 blocks x 1024)
  int v0 = 0, v1 = 0;
  for (int s = 0; s < 376; ++s) {
    const int rb0 = v0 & 1, rb1 = v1 & 1;
    bool up0 = false, up1 = false;
    if (s <= 256) {  // ---- prefix: L0@t=s (WG 0-127) || L1@t=s-1 (WG 128-255)
      up0 = (s <= 255);
      up1 = (s >= 1);
      if (w < 128) {
        if (s <= 255) {
          ZACC;
          gemm_item(XH + (long)s * 32768, H0H + rb0 * HS, 32,
                    S0 + (long)w * 40960, 10, ldsB, tid, acc);
          epilogue_gates(acc, w * 32, B0P, C0 + w * 1024, hTile,
                         H0H + (1 - rb0) * HS + w * 1024, tid);
        }
      } else {
        if (s >= 1) {
          ZACC;
          const int bw = w - 128;
          gemm_item(H0H + rb0 * HS, H1H + rb1 * HS, 128,
                    S1 + (long)bw * 65536, 16, ldsB, tid, acc);
          epilogue_gates(acc, bw * 32, B1P, C1 + bw * 1024, hTile,
                         H1H + (1 - rb1) * HS + bw * 1024, tid);
        }
      }
    } else if (s < 375) {  // ---- decode ----
      const int d = s - 257;
      if ((d & 1) == 0) {  // cell0 (Weff-fused) + y output columns
        up0 = true;
        const int i = d >> 1;
        if (w < 128) {
          ZACC;
          gemm_item(H1H + rb1 * HS, H0H + rb0 * HS, 128,
                    SD + (long)w * 65536, 16, ldsB, tid, acc);
          epilogue_gates(acc, w * 32, BD0P, C0 + w * 1024, hTile,
                         H0H + (1 - rb0) * HS + w * 1024, tid);
        } else if (w < 136) {
          ZACC;
          const int ww = w - 128;
          gemm_item(H1H + rb1 * HS, H1H + rb1 * HS, 128,
                    SY + (long)ww * 32768, 8, ldsB, tid, acc);
          epilogue_y(acc, ww * 32, BD0P + 4096, out + i * 256, tid);
        }
      } else {  // cell1
        up1 = true;
        if (w < 128) {
          ZACC;
          gemm_item(H0H + rb0 * HS, H1H + rb1 * HS, 128,
                    S1 + (long)w * 65536, 16, ldsB, tid, acc);
          epilogue_gates(acc, w * 32, B1P, C1 + w * 1024, hTile,
                         H1H + (1 - rb1) * HS + w * 1024, tid);
        }
      }
    } else {  // ---- s == 375: final y (step 59) ----
      if (w < 8) {
        ZACC;
        gemm_item(H1H + rb1 * HS, H1H + rb1 * HS, 128,
                  SY + (long)w * 32768, 8, ldsB, tid, acc);
        epilogue_y(acc, w * 32, BD0P + 4096, out + 59 * 256, tid);
      }
    }
    grid_barrier(cnt, (s + 1) * 256);
    if (up0) v0++;
    if (up1) v1++;
  }
}

// ======================= setup kernels =======================

// x[B,T,D] fp32 -> XH[t][kblock][row][8] fp16
__global__ void k_cvt_x(const float* __restrict__ x, half_t* __restrict__ XH) {
  int idx = blockIdx.x * 256 + threadIdx.x;  // 1,048,576 total
  int t = idx >> 12;
  int kb = (idx >> 7) & 31;
  int r = idx & 127;
  const float* src = x + ((long)((r << 8) + t)) * 256 + kb * 8;
  float4 v0 = *(const float4*)src;
  float4 v1 = *(const float4*)(src + 4);
  half_t tmp[8] = {(half_t)v0.x, (half_t)v0.y, (half_t)v0.z, (half_t)v0.w,
                   (half_t)v1.x, (half_t)v1.y, (half_t)v1.z, (half_t)v1.w};
  *(uint4*)(XH + (long)t * 32768 + kb * 1024 + r * 8) = *(const uint4*)tmp;
}

// Pack gate-weight rows (gate-interleaved permutation row' = 4*unit+gate)
// into per-WG fragment-linear streams. Source k = c*128+b*8 taken from A
// (stride KA) when k<KA else Bsrc (stride 1024). Dest chunk index = c0+c.
__global__ void k_pack_gates(const float* __restrict__ A, int KA,
                             const float* __restrict__ Bsrc,
                             half_t* __restrict__ dst, int nch, int c0,
                             int wnch) {
  int idx = blockIdx.x * 256 + threadIdx.x;
  int nn = idx & 31;
  int b = (idx >> 5) & 15;
  int t = idx >> 9;
  int c = t % nch;
  int w = t / nch;
  int rp = w * 32 + nn;
  int r = ((rp & 3) << 10) + (rp >> 2);
  int k = c * 128 + b * 8;
  const float* src = (k < KA) ? (A + (long)r * KA + k)
                              : (Bsrc + (long)r * 1024 + (k - KA));
  float4 v0 = *(const float4*)src;
  float4 v1 = *(const float4*)(src + 4);
  half_t tmp[8] = {(half_t)v0.x, (half_t)v0.y, (half_t)v0.z, (half_t)v0.w,
                   (half_t)v1.x, (half_t)v1.y, (half_t)v1.z, (half_t)v1.w};
  *(uint4*)(dst + (long)(w * wnch + c0 + c) * 4096 + b * 256 + nn * 8) =
      *(const uint4*)tmp;
}

// W_lin rows (no gate permutation) -> y-stream [ww][chunk][16][32][8]
__global__ void k_pack_y(const float* __restrict__ Wlin,
                         half_t* __restrict__ SY) {
  int idx = blockIdx.x * 256 + threadIdx.x;  // 32768 total
  int nn = idx & 31;
  int b = (idx >> 5) & 15;
  int c = (idx >> 9) & 7;
  int ww = idx >> 12;
  int d = ww * 32 + nn;
  int k = c * 128 + b * 8;
  const float* src = Wlin + (long)d * 1024 + k;
  float4 v0 = *(const float4*)src;
  float4 v1 = *(const float4*)(src + 4);
  half_t tmp[8] = {(half_t)v0.x, (half_t)v0.y, (half_t)v0.z, (half_t)v0.w,
                   (half_t)v1.x, (half_t)v1.y, (half_t)v1.z, (half_t)v1.w};
  *(uint4*)(SY + (long)(ww * 8 + c) * 4096 + b * 256 + nn * 8) =
      *(const uint4*)tmp;
}

__global__ void k_bias_simple(const float* bi0, const float* bh0,
                              const float* bi1, const float* bh1,
                              const float* blin, float* b0p, float* b1p,
                              float* bD0p) {
  int rp = blockIdx.x * blockDim.x + threadIdx.x;
  if (rp < 4096) {
    int r = ((rp & 3) << 10) + (rp >> 2);
    b0p[rp] = bi0[r] + bh0[r];
    b1p[rp] = bi1[r] + bh1[r];
  } else if (rp < 4352) {
    bD0p[rp] = blin[rp - 4096];
  }
}

// biasD0p[row'] = b_ih0[r] + b_hh0[r] + dot(W_ih0[r,:], b_lin)
__global__ void k_bias_dot(const float* __restrict__ Wih0,
                           const float* __restrict__ blin,
                           const float* __restrict__ bi0,
                           const float* __restrict__ bh0,
                           float* __restrict__ bD0p) {
  int wv = threadIdx.x >> 6, l = threadIdx.x & 63;
  int r = blockIdx.x * 4 + wv;
  float s = 0.f;
#pragma unroll
  for (int c = 0; c < 4; ++c) s += Wih0[r * 256 + c * 64 + l] * blin[c * 64 + l];
#pragma unroll
  for (int o = 32; o >= 1; o >>= 1) s += __shfl_xor(s, o);
  if (l == 0) {
    int rp = ((r & 1023) << 2) | (r >> 10);
    bD0p[rp] = bi0[r] + bh0[r] + s;
  }
}

// Weff = W_ih0(4096x256) @ W_lin(256x1024); written fp16 directly into the
// SD stream (chunks 0..7, fragment-linear, gate-permuted rows).
__global__ void k_weff(const float* __restrict__ Wih0,
                       const float* __restrict__ Wlin,
                       half_t* __restrict__ SD) {
  __shared__ float At[64][65];
  __shared__ float Bt[64][65];
  const int rt = blockIdx.x, jt = blockIdx.y;
  const int tid = threadIdx.x;
  const int tx = tid & 15, ty = tid >> 4;
  float acc[4][4] = {};
  for (int k0 = 0; k0 < 256; k0 += 64) {
    __syncthreads();
#pragma unroll
    for (int i = 0; i < 16; ++i) {
      int lin = tid + 256 * i;
      int rr = lin >> 6, kk = lin & 63;
      At[rr][kk] = Wih0[(rt * 64 + rr) * 256 + k0 + kk];
      Bt[rr][kk] = Wlin[(k0 + rr) * 1024 + jt * 64 + kk];
    }
    __syncthreads();
    for (int kk = 0; kk < 64; ++kk) {
      float a[4], b[4];
#pragma unroll
      for (int i = 0; i < 4; ++i) a[i] = At[ty * 4 + i][kk];
#pragma unroll
      for (int i = 0; i < 4; ++i) b[i] = Bt[kk][tx * 4 + i];
#pragma unroll
      for (int i = 0; i < 4; ++i)
#pragma unroll
        for (int jx = 0; jx < 4; ++jx) acc[i][jx] += a[i] * b[jx];
    }
  }
#pragma unroll
  for (int i = 0; i < 4; ++i) {
    int r = rt * 64 + ty * 4 + i;
    int rp = ((r & 1023) << 2) | (r >> 10);
    int w = rp >> 5, nn = rp & 31;
#pragma unroll
    for (int jx = 0; jx < 4; ++jx) {
      int j = jt * 64 + tx * 4 + jx;
      SD[(long)w * 65536 + (j >> 7) * 4096 + ((j >> 3) & 15) * 256 + nn * 8 +
         (j & 7)] = (half_t)acc[i][jx];
    }
  }
}

// ======================= launch =======================

extern "C" void kernel_launch(void* const* d_in, const int* in_sizes, int n_in,
                              void* d_out, int out_size, void* d_ws, size_t ws_size,
                              hipStream_t stream) {
  (void)in_sizes; (void)n_in; (void)out_size; (void)ws_size;
  const float* x    = (const float*)d_in[0];
  const float* Wih0 = (const float*)d_in[1];
  const float* Whh0 = (const float*)d_in[2];
  const float* bi0  = (const float*)d_in[3];
  const float* bh0  = (const float*)d_in[4];
  const float* Wih1 = (const float*)d_in[5];
  const float* Whh1 = (const float*)d_in[6];
  const float* bi1  = (const float*)d_in[7];
  const float* bh1  = (const float*)d_in[8];
  const float* Wlin = (const float*)d_in[9];
  const float* blin = (const float*)d_in[10];
  float* out = (float*)d_out;
  char* ws = (char*)d_ws;

  half_t* S0  = (half_t*)(ws + 0);         // 128 WG x 10 chunks x 8KB = 10 MB
  half_t* S1  = (half_t*)(ws + 10485760);  // 128 x 16 x 8KB = 16 MB
  half_t* SD  = (half_t*)(ws + 27262976);  // 128 x 16 x 8KB = 16 MB
  half_t* SY  = (half_t*)(ws + 44040192);  // 8 x 8 x 8KB = 512 KB
  half_t* XH  = (half_t*)(ws + 44564480);  // 16 MB, [t][kb][row][8]
  half_t* H0H = (half_t*)(ws + 61341696);  // 2 x 256 KB
  half_t* H1H = (half_t*)(ws + 61865984);
  float*  C0  = (float*)(ws + 62390272);   // 512 KB, [blk][row][8]
  float*  C1  = (float*)(ws + 62914560);
  float*  B0P = (float*)(ws + 63438848);
  float*  B1P = (float*)(ws + 63455232);
  float*  BD0P= (float*)(ws + 63471616);
  int*    CNT = (int*)(ws + 63489024);
  // total ws needed: 63,489,280 bytes

  // zero h/c state + bias region + barrier counter
  hipMemsetAsync(ws + 61341696, 0, 2147584, stream);
  k_cvt_x<<<4096, 256, 0, stream>>>(x, XH);
  k_bias_simple<<<17, 256, 0, stream>>>(bi0, bh0, bi1, bh1, blin, B0P, B1P, BD0P);
  k_bias_dot<<<1024, 256, 0, stream>>>(Wih0, blin, bi0, bh0, BD0P);
  k_pack_gates<<<2560, 256, 0, stream>>>(Wih0, 256, Whh0, S0, 10, 0, 10);
  k_pack_gates<<<4096, 256, 0, stream>>>(Wih1, 1024, Whh1, S1, 16, 0, 16);
  k_pack_gates<<<2048, 256, 0, stream>>>(Whh0, 0, Whh0, SD, 8, 8, 16);
  k_pack_y<<<128, 256, 0, stream>>>(Wlin, SY);
  k_weff<<<dim3(64, 16), 256, 0, stream>>>(Wih0, Wlin, SD);
  k_lstm<<<256, 256, 0, stream>>>(S0, S1, SD, SY, XH, H0H, H1H, C0, C1,
                                  B0P, B1P, BD0P, out, CNT);
}

// Round 3
// 9615.617 us; speedup vs baseline: 3.6427x; 3.4503x over previous
//
#include <hip/hip_runtime.h>
#include <hip/hip_bf16.h>
#include <cstdint>

// ============================================================================
// 2-layer LSTM prefix + 59-step decode, persistent kernel, round 3.
// Round-3 changes (theory: round-2 was killed by per-step whole-L2
// writeback/invalidate storms from __threadfence + acquire polling):
//   * NO cache-maintenance ops at all. Cross-WG data (h state, barrier
//     counter) goes through the device coherence point (IF$) via sc1
//     device-scope accesses; everything else (weights, XH, c) uses normal
//     L1/L2-cached loads and stays resident across steps.
//   * W tile staged to LDS ONCE per step (<=128 KB), no per-chunk barriers.
//   * decode cell1 runs on blocks 128-255 (C1 stays block-private, since
//     without fences c-state is only coherent within its own CU).
// ============================================================================

typedef _Float16 half_t;
typedef _Float16 half8 __attribute__((ext_vector_type(8)));
typedef float float4v __attribute__((ext_vector_type(4)));
typedef int int32x4_t __attribute__((ext_vector_type(4)));
typedef float float32x4_t __attribute__((ext_vector_type(4)));

// CK-style raw buffer load (compiler-tracked, schedulable, carries cache bits)
__device__ float32x4_t llvm_amdgcn_raw_buffer_load_fp32x4(
    int32x4_t srsrc, int voffset, int soffset, int aux)
    __asm("llvm.amdgcn.raw.buffer.load.v4f32");

#define AUX_SC1 16  // CPol SCC bit -> sc1: device-scope, bypass L1/L2, hit IF$

union SrdU {
  int32x4_t v;
  struct { const void* p; unsigned nr, fl; } s;
};

__device__ __forceinline__ int32x4_t make_srd(const void* p) {
  SrdU u;
  u.s.p = p;               // 48-bit VA, bits 63:48 are 0 -> stride field 0
  u.s.nr = 0xFFFFFFFFu;    // disable bounds check
  u.s.fl = 0x00020000u;    // raw dword access
  return u.v;
}

__device__ __forceinline__ half8 bufld(int32x4_t srd, int voff) {
  union { float32x4_t f; half8 h; } u;
  u.f = llvm_amdgcn_raw_buffer_load_fp32x4(srd, voff, 0, AUX_SC1);
  return u.h;
}

__device__ __forceinline__ float sigm_(float x) { return 1.0f / (1.0f + __expf(-x)); }
__device__ __forceinline__ float tanh_(float x) {
  float ax = fabsf(x);
  float e = __expf(-2.0f * ax);
  float t = (1.0f - e) / (1.0f + e);
  return x < 0.0f ? -t : t;
}

// Grid barrier: RELAXED device-scope atomics only — no buffer_wbl2/buffer_inv.
// Release: __syncthreads drains vmcnt(0) per wave (sc1 stores ack at IF$).
// Acquire: sc1 loads never cache -> no invalidate needed; asm memory clobbers
// stop compiler-level reordering; HW issues in order per wave.
__device__ __forceinline__ void grid_barrier(int* cnt, int target) {
  asm volatile("" ::: "memory");
  __syncthreads();
  if (threadIdx.x == 0) {
    __hip_atomic_fetch_add(cnt, 1, __ATOMIC_RELAXED, __HIP_MEMORY_SCOPE_AGENT);
    while (__hip_atomic_load(cnt, __ATOMIC_RELAXED, __HIP_MEMORY_SCOPE_AGENT) < target) {
      __builtin_amdgcn_s_sleep(8);
    }
  }
  __syncthreads();
  asm volatile("" ::: "memory");
}

#define MFMA16(a, b, c) __builtin_amdgcn_mfma_f32_16x16x32_f16(a, b, c, 0, 0, 0)

// C = A(128 x K) * W(32 x K)^T for one WG. A = concat(A0, A1) in 8-k blocks
// (K0b blocks from A0). A is fragment-linear [block][128][8].
// W stream (nch * 8 KB) staged fully into LDS once, then barrier-free K-loop.
// COH0=false: A0 read with normal (cached) loads — for read-only XH.
// h sources are read with sc1 buffer loads (device-coherent, IF$).
template <bool COH0>
__device__ __forceinline__ void gemm_item(
    const half_t* __restrict__ A0, const half_t* __restrict__ A1, int K0b,
    const half_t* __restrict__ Wst, int nch,
    half_t* ldsW, int tid, float4v acc[2][2]) {
  const int wv = tid >> 6, l = tid & 63;
  const int lrow = l & 15, lq = l >> 4;

  // ---- stage full W stream into LDS (linear copy, wave-partitioned) ----
  {
    const int perB = nch * 2048;  // bytes per wave
    const char* gp = (const char*)Wst + (long)wv * perB + l * 16;
    char* lp = (char*)ldsW + wv * perB + l * 16;
    for (int i = 0; i < perB; i += 4096) {
      uint4 t0 = *(const uint4*)(gp + i);
      uint4 t1 = *(const uint4*)(gp + i + 1024);
      uint4 t2 = *(const uint4*)(gp + i + 2048);
      uint4 t3 = *(const uint4*)(gp + i + 3072);
      *(uint4*)(lp + i) = t0;
      *(uint4*)(lp + i + 1024) = t1;
      *(uint4*)(lp + i + 2048) = t2;
      *(uint4*)(lp + i + 3072) = t3;
    }
  }
  const int32x4_t srd0 = make_srd(A0);
  const int32x4_t srd1 = make_srd(A1);
  const int K0c = K0b >> 4;  // chunks from A0
  const int voB = (wv * 32 + lrow) * 16;
  __syncthreads();

  for (int c = 0; c < nch; ++c) {
    const bool useA0 = (c < K0c);
    const half_t* bp = ldsW + c * 4096 + lrow * 8;
#pragma unroll
    for (int ks = 0; ks < 4; ++ks) {
      const int blk = ks * 4 + lq;
      half8 af0, af1;
      if (!COH0 && useA0) {
        const half_t* ap = A0 + (long)c * 16384 + (wv * 32 + lrow) * 8 + blk * 1024;
        af0 = *(const half8*)ap;
        af1 = *(const half8*)(ap + 128);
      } else {
        const int32x4_t srd = useA0 ? srd0 : srd1;
        const int off = (useA0 ? c : c - K0c) * 32768 + voB + blk * 2048;
        af0 = bufld(srd, off);
        af1 = bufld(srd, off + 256);
      }
      half8 bf0 = *(const half8*)(bp + blk * 256);
      half8 bf1 = *(const half8*)(bp + blk * 256 + 128);
      acc[0][0] = MFMA16(af0, bf0, acc[0][0]);
      acc[0][1] = MFMA16(af0, bf1, acc[0][1]);
      acc[1][0] = MFMA16(af1, bf0, acc[1][0]);
      acc[1][1] = MFMA16(af1, bf1, acc[1][1]);
    }
  }
  __syncthreads();  // ldsW reused next step; also drains before epilogue use
}

// Cell epilogue for a [128 x 32] gate tile (cols = 8 units x 4 gates).
// D layout: col = lane&15, row = (lane>>4)*4 + reg. Gates of one unit live in
// a quad; lane q keeps reg r==q. c in private [row][8] fp32 block (normal,
// CU-local); h staged via LDS then stored DEVICE-SCOPE (sc1) for cross-XCD
// visibility.
__device__ __forceinline__ void epilogue_gates(
    float4v acc[2][2], int col0, const float* __restrict__ biasArr,
    float* __restrict__ Cblk, half_t* hTile, half_t* __restrict__ hDstBlk,
    int tid) {
  const int wv = tid >> 6, l = tid & 63;
  const int lrow = l & 15, lq = l >> 4, q = l & 3;
  const int a = lrow >> 2;
#pragma unroll
  for (int m = 0; m < 2; ++m)
#pragma unroll
    for (int n = 0; n < 2; ++n) {
      const float bias = biasArr[col0 + n * 16 + lrow];
      float gi = 0.f, gf = 0.f, gg = 0.f, go = 0.f;
#pragma unroll
      for (int r = 0; r < 4; ++r) {
        float x = acc[m][n][r] + bias;
        float t1 = __shfl_xor(x, 1);
        float t2 = __shfl_xor(x, 2);
        float t3 = __shfl_xor(x, 3);
        if (r == q) {
          gi = (q == 0) ? x : (q == 1 ? t1 : (q == 2 ? t2 : t3));
          gf = (q == 1) ? x : (q == 0 ? t1 : (q == 3 ? t2 : t3));
          gg = (q == 2) ? x : (q == 3 ? t1 : (q == 0 ? t2 : t3));
          go = (q == 3) ? x : (q == 2 ? t1 : (q == 1 ? t2 : t3));
        }
      }
      const int row = wv * 32 + m * 16 + lq * 4 + q;
      const int jj = n * 4 + a;
      float iv = sigm_(gi), fv = sigm_(gf), gv = tanh_(gg), ov = sigm_(go);
      float cold = Cblk[row * 8 + jj];
      float cnew = fv * cold + iv * gv;
      float hnew = ov * tanh_(cnew);
      Cblk[row * 8 + jj] = cnew;
      hTile[row * 8 + jj] = (half_t)hnew;
    }
  __syncthreads();
  if (tid < 128) {
    const unsigned long long* src = (const unsigned long long*)(hTile + tid * 8);
    unsigned long long* dst = (unsigned long long*)(hDstBlk + tid * 8);
    unsigned long long v0 = src[0], v1 = src[1];
    __hip_atomic_store(dst, v0, __ATOMIC_RELAXED, __HIP_MEMORY_SCOPE_AGENT);
    __hip_atomic_store(dst + 1, v1, __ATOMIC_RELAXED, __HIP_MEMORY_SCOPE_AGENT);
  }
}

__device__ __forceinline__ void epilogue_y(
    float4v acc[2][2], int ycol0, const float* __restrict__ biasArr,
    float* __restrict__ outp, int tid) {
  const int wv = tid >> 6, l = tid & 63;
  const int lrow = l & 15, lq = l >> 4;
#pragma unroll
  for (int m = 0; m < 2; ++m)
#pragma unroll
    for (int n = 0; n < 2; ++n) {
      const int d = ycol0 + n * 16 + lrow;
      const float bias = biasArr[d];
      const int rb = wv * 32 + m * 16 + lq * 4;
#pragma unroll
      for (int r = 0; r < 4; ++r) {
        outp[(rb + r) * 15360 + d] = acc[m][n][r] + bias;
      }
    }
}

#define ZACC float4v acc[2][2]; { float4v z = {0.f, 0.f, 0.f, 0.f}; \
  acc[0][0] = z; acc[0][1] = z; acc[1][0] = z; acc[1][1] = z; }

__global__ void __launch_bounds__(256, 1) k_lstm(
    const half_t* __restrict__ S0, const half_t* __restrict__ S1,
    const half_t* __restrict__ SD, const half_t* __restrict__ SY,
    const half_t* __restrict__ XH,
    half_t* __restrict__ H0H, half_t* __restrict__ H1H,
    float* __restrict__ C0, float* __restrict__ C1,
    const float* __restrict__ B0P, const float* __restrict__ B1P,
    const float* __restrict__ BD0P, float* __restrict__ out, int* cnt) {
  __shared__ half_t ldsW[65536];  // 128 KB W stage
  __shared__ half_t hTile[1024];  // 2 KB h epilogue staging
  const int w = blockIdx.x, tid = threadIdx.x;
  const int HS = 131072;  // one h buffer in halves
  int v0 = 0, v1 = 0;
  for (int s = 0; s < 376; ++s) {
    const int rb0 = v0 & 1, rb1 = v1 & 1;
    bool up0 = false, up1 = false;
    if (s <= 256) {  // ---- prefix: L0@t=s (WG 0-127) || L1@t=s-1 (WG 128-255)
      up0 = (s <= 255);
      up1 = (s >= 1);
      if (w < 128) {
        if (s <= 255) {
          ZACC;
          gemm_item<false>(XH + (long)s * 32768, H0H + rb0 * HS, 32,
                           S0 + (long)w * 40960, 10, ldsW, tid, acc);
          epilogue_gates(acc, w * 32, B0P, C0 + w * 1024, hTile,
                         H0H + (1 - rb0) * HS + w * 1024, tid);
        }
      } else {
        if (s >= 1) {
          ZACC;
          const int bw = w - 128;
          gemm_item<true>(H0H + rb0 * HS, H1H + rb1 * HS, 128,
                          S1 + (long)bw * 65536, 16, ldsW, tid, acc);
          epilogue_gates(acc, bw * 32, B1P, C1 + bw * 1024, hTile,
                         H1H + (1 - rb1) * HS + bw * 1024, tid);
        }
      }
    } else if (s < 375) {  // ---- decode ----
      const int d = s - 257;
      if ((d & 1) == 0) {  // cell0 (Weff-fused, blocks 0-127) + y (128-135)
        up0 = true;
        const int i = d >> 1;
        if (w < 128) {
          ZACC;
          gemm_item<true>(H1H + rb1 * HS, H0H + rb0 * HS, 128,
                          SD + (long)w * 65536, 16, ldsW, tid, acc);
          epilogue_gates(acc, w * 32, BD0P, C0 + w * 1024, hTile,
                         H0H + (1 - rb0) * HS + w * 1024, tid);
        } else if (w < 136) {
          ZACC;
          const int ww = w - 128;
          gemm_item<true>(H1H + rb1 * HS, H1H + rb1 * HS, 128,
                          SY + (long)ww * 32768, 8, ldsW, tid, acc);
          epilogue_y(acc, ww * 32, BD0P + 4096, out + i * 256, tid);
        }
      } else {  // cell1 on blocks 128-255 (they own C1 from the prefix)
        up1 = true;
        if (w >= 128) {
          ZACC;
          const int bw = w - 128;
          gemm_item<true>(H0H + rb0 * HS, H1H + rb1 * HS, 128,
                          S1 + (long)bw * 65536, 16, ldsW, tid, acc);
          epilogue_gates(acc, bw * 32, B1P, C1 + bw * 1024, hTile,
                         H1H + (1 - rb1) * HS + bw * 1024, tid);
        }
      }
    } else {  // ---- s == 375: final y (step 59) ----
      if (w < 8) {
        ZACC;
        gemm_item<true>(H1H + rb1 * HS, H1H + rb1 * HS, 128,
                        SY + (long)w * 32768, 8, ldsW, tid, acc);
        epilogue_y(acc, w * 32, BD0P + 4096, out + 59 * 256, tid);
      }
    }
    grid_barrier(cnt, (s + 1) * 256);
    if (up0) v0++;
    if (up1) v1++;
  }
}

// ======================= setup kernels =======================

// x[B,T,D] fp32 -> XH[t][kblock][row][8] fp16
__global__ void k_cvt_x(const float* __restrict__ x, half_t* __restrict__ XH) {
  int idx = blockIdx.x * 256 + threadIdx.x;  // 1,048,576 total
  int t = idx >> 12;
  int kb = (idx >> 7) & 31;
  int r = idx & 127;
  const float* src = x + ((long)((r << 8) + t)) * 256 + kb * 8;
  float4 v0 = *(const float4*)src;
  float4 v1 = *(const float4*)(src + 4);
  half_t tmp[8] = {(half_t)v0.x, (half_t)v0.y, (half_t)v0.z, (half_t)v0.w,
                   (half_t)v1.x, (half_t)v1.y, (half_t)v1.z, (half_t)v1.w};
  *(uint4*)(XH + (long)t * 32768 + kb * 1024 + r * 8) = *(const uint4*)tmp;
}

// Pack gate-weight rows (gate-interleaved permutation row' = 4*unit+gate)
// into per-WG fragment-linear streams. Source k = c*128+b*8 taken from A
// (stride KA) when k<KA else Bsrc (stride 1024). Dest chunk index = c0+c.
__global__ void k_pack_gates(const float* __restrict__ A, int KA,
                             const float* __restrict__ Bsrc,
                             half_t* __restrict__ dst, int nch, int c0,
                             int wnch) {
  int idx = blockIdx.x * 256 + threadIdx.x;
  int nn = idx & 31;
  int b = (idx >> 5) & 15;
  int t = idx >> 9;
  int c = t % nch;
  int w = t / nch;
  int rp = w * 32 + nn;
  int r = ((rp & 3) << 10) + (rp >> 2);
  int k = c * 128 + b * 8;
  const float* src = (k < KA) ? (A + (long)r * KA + k)
                              : (Bsrc + (long)r * 1024 + (k - KA));
  float4 v0 = *(const float4*)src;
  float4 v1 = *(const float4*)(src + 4);
  half_t tmp[8] = {(half_t)v0.x, (half_t)v0.y, (half_t)v0.z, (half_t)v0.w,
                   (half_t)v1.x, (half_t)v1.y, (half_t)v1.z, (half_t)v1.w};
  *(uint4*)(dst + (long)(w * wnch + c0 + c) * 4096 + b * 256 + nn * 8) =
      *(const uint4*)tmp;
}

// W_lin rows (no gate permutation) -> y-stream [ww][chunk][16][32][8]
__global__ void k_pack_y(const float* __restrict__ Wlin,
                         half_t* __restrict__ SY) {
  int idx = blockIdx.x * 256 + threadIdx.x;  // 32768 total
  int nn = idx & 31;
  int b = (idx >> 5) & 15;
  int c = (idx >> 9) & 7;
  int ww = idx >> 12;
  int d = ww * 32 + nn;
  int k = c * 128 + b * 8;
  const float* src = Wlin + (long)d * 1024 + k;
  float4 v0 = *(const float4*)src;
  float4 v1 = *(const float4*)(src + 4);
  half_t tmp[8] = {(half_t)v0.x, (half_t)v0.y, (half_t)v0.z, (half_t)v0.w,
                   (half_t)v1.x, (half_t)v1.y, (half_t)v1.z, (half_t)v1.w};
  *(uint4*)(SY + (long)(ww * 8 + c) * 4096 + b * 256 + nn * 8) =
      *(const uint4*)tmp;
}

__global__ void k_bias_simple(const float* bi0, const float* bh0,
                              const float* bi1, const float* bh1,
                              const float* blin, float* b0p, float* b1p,
                              float* bD0p) {
  int rp = blockIdx.x * blockDim.x + threadIdx.x;
  if (rp < 4096) {
    int r = ((rp & 3) << 10) + (rp >> 2);
    b0p[rp] = bi0[r] + bh0[r];
    b1p[rp] = bi1[r] + bh1[r];
  } else if (rp < 4352) {
    bD0p[rp] = blin[rp - 4096];
  }
}

// biasD0p[row'] = b_ih0[r] + b_hh0[r] + dot(W_ih0[r,:], b_lin)
__global__ void k_bias_dot(const float* __restrict__ Wih0,
                           const float* __restrict__ blin,
                           const float* __restrict__ bi0,
                           const float* __restrict__ bh0,
                           float* __restrict__ bD0p) {
  int wv = threadIdx.x >> 6, l = threadIdx.x & 63;
  int r = blockIdx.x * 4 + wv;
  float s = 0.f;
#pragma unroll
  for (int c = 0; c < 4; ++c) s += Wih0[r * 256 + c * 64 + l] * blin[c * 64 + l];
#pragma unroll
  for (int o = 32; o >= 1; o >>= 1) s += __shfl_xor(s, o);
  if (l == 0) {
    int rp = ((r & 1023) << 2) | (r >> 10);
    bD0p[rp] = bi0[r] + bh0[r] + s;
  }
}

// Weff = W_ih0(4096x256) @ W_lin(256x1024); written fp16 directly into the
// SD stream (chunks 0..7, fragment-linear, gate-permuted rows).
__global__ void k_weff(const float* __restrict__ Wih0,
                       const float* __restrict__ Wlin,
                       half_t* __restrict__ SD) {
  __shared__ float At[64][65];
  __shared__ float Bt[64][65];
  const int rt = blockIdx.x, jt = blockIdx.y;
  const int tid = threadIdx.x;
  const int tx = tid & 15, ty = tid >> 4;
  float acc[4][4] = {};
  for (int k0 = 0; k0 < 256; k0 += 64) {
    __syncthreads();
#pragma unroll
    for (int i = 0; i < 16; ++i) {
      int lin = tid + 256 * i;
      int rr = lin >> 6, kk = lin & 63;
      At[rr][kk] = Wih0[(rt * 64 + rr) * 256 + k0 + kk];
      Bt[rr][kk] = Wlin[(k0 + rr) * 1024 + jt * 64 + kk];
    }
    __syncthreads();
    for (int kk = 0; kk < 64; ++kk) {
      float a[4], b[4];
#pragma unroll
      for (int i = 0; i < 4; ++i) a[i] = At[ty * 4 + i][kk];
#pragma unroll
      for (int i = 0; i < 4; ++i) b[i] = Bt[kk][tx * 4 + i];
#pragma unroll
      for (int i = 0; i < 4; ++i)
#pragma unroll
        for (int jx = 0; jx < 4; ++jx) acc[i][jx] += a[i] * b[jx];
    }
  }
#pragma unroll
  for (int i = 0; i < 4; ++i) {
    int r = rt * 64 + ty * 4 + i;
    int rp = ((r & 1023) << 2) | (r >> 10);
    int w = rp >> 5, nn = rp & 31;
#pragma unroll
    for (int jx = 0; jx < 4; ++jx) {
      int j = jt * 64 + tx * 4 + jx;
      SD[(long)w * 65536 + (j >> 7) * 4096 + ((j >> 3) & 15) * 256 + nn * 8 +
         (j & 7)] = (half_t)acc[i][jx];
    }
  }
}

// ======================= launch =======================

extern "C" void kernel_launch(void* const* d_in, const int* in_sizes, int n_in,
                              void* d_out, int out_size, void* d_ws, size_t ws_size,
                              hipStream_t stream) {
  (void)in_sizes; (void)n_in; (void)out_size; (void)ws_size;
  const float* x    = (const float*)d_in[0];
  const float* Wih0 = (const float*)d_in[1];
  const float* Whh0 = (const float*)d_in[2];
  const float* bi0  = (const float*)d_in[3];
  const float* bh0  = (const float*)d_in[4];
  const float* Wih1 = (const float*)d_in[5];
  const float* Whh1 = (const float*)d_in[6];
  const float* bi1  = (const float*)d_in[7];
  const float* bh1  = (const float*)d_in[8];
  const float* Wlin = (const float*)d_in[9];
  const float* blin = (const float*)d_in[10];
  float* out = (float*)d_out;
  char* ws = (char*)d_ws;

  half_t* S0  = (half_t*)(ws + 0);         // 128 WG x 10 chunks x 8KB = 10 MB
  half_t* S1  = (half_t*)(ws + 10485760);  // 128 x 16 x 8KB = 16 MB
  half_t* SD  = (half_t*)(ws + 27262976);  // 128 x 16 x 8KB = 16 MB
  half_t* SY  = (half_t*)(ws + 44040192);  // 8 x 8 x 8KB = 512 KB
  half_t* XH  = (half_t*)(ws + 44564480);  // 16 MB, [t][kb][row][8]
  half_t* H0H = (half_t*)(ws + 61341696);  // 2 x 256 KB
  half_t* H1H = (half_t*)(ws + 61865984);
  float*  C0  = (float*)(ws + 62390272);   // 512 KB, [blk][row][8]
  float*  C1  = (float*)(ws + 62914560);
  float*  B0P = (float*)(ws + 63438848);
  float*  B1P = (float*)(ws + 63455232);
  float*  BD0P= (float*)(ws + 63471616);
  int*    CNT = (int*)(ws + 63489024);
  // total ws needed: 63,489,280 bytes

  // zero h/c state + bias region + barrier counter
  hipMemsetAsync(ws + 61341696, 0, 2147584, stream);
  k_cvt_x<<<4096, 256, 0, stream>>>(x, XH);
  k_bias_simple<<<17, 256, 0, stream>>>(bi0, bh0, bi1, bh1, blin, B0P, B1P, BD0P);
  k_bias_dot<<<1024, 256, 0, stream>>>(Wih0, blin, bi0, bh0, BD0P);
  k_pack_gates<<<2560, 256, 0, stream>>>(Wih0, 256, Whh0, S0, 10, 0, 10);
  k_pack_gates<<<4096, 256, 0, stream>>>(Wih1, 1024, Whh1, S1, 16, 0, 16);
  k_pack_gates<<<2048, 256, 0, stream>>>(Whh0, 0, Whh0, SD, 8, 8, 16);
  k_pack_y<<<128, 256, 0, stream>>>(Wlin, SY);
  k_weff<<<dim3(64, 16), 256, 0, stream>>>(Wih0, Wlin, SD);
  k_lstm<<<256, 256, 0, stream>>>(S0, S1, SD, SY, XH, H0H, H1H, C0, C1,
                                  B0P, B1P, BD0P, out, CNT);
}